// Round 3
// baseline (65.591 us; speedup 1.0000x reference)
//
#include <hip/hip_runtime.h>

#define SAMPLES 32
#define ELEMS_PER_SAMPLE (256 * 64 * 64)              // 1048576
#define VEC4_PER_SAMPLE (ELEMS_PER_SAMPLE / 4)        // 262144
#define BLOCKS_PER_SAMPLE 64
#define THREADS 256
#define GRID (SAMPLES * BLOCKS_PER_SAMPLE)            // 2048
#define ITERS (VEC4_PER_SAMPLE / (BLOCKS_PER_SAMPLE * THREADS))  // 16

#define BETA 2.0f
#define EPS 1e-5f

typedef float f32x4 __attribute__((ext_vector_type(4)));

__device__ __forceinline__ float wave_reduce_sum(float v) {
#pragma unroll
    for (int off = 32; off > 0; off >>= 1)
        v += __shfl_down(v, off, 64);
    return v;
}

// ws layout (floats):
//   [0 .. 2*GRID)        per-block (sum, sumsq) pairs from kernel 1
//   [2*GRID .. 3*GRID)   per-block loss partials from kernel 2
#define LPART_OFF (2 * GRID)

// ---------------- Kernel 1: per-block teacher partial sum/sumsq ----------------
// Teacher loads are REGULAR: we want teacher resident in L3 for kernel 2.
__global__ __launch_bounds__(THREADS) void kd_stats_kernel(
    const float4* __restrict__ t, float* __restrict__ ws) {
    const float4* base = t + (size_t)blockIdx.x * (THREADS * ITERS);

    float sum = 0.0f, sumsq = 0.0f;
#pragma unroll
    for (int i = 0; i < ITERS; ++i) {
        float4 v = base[i * THREADS + threadIdx.x];
        sum += v.x + v.y + v.z + v.w;
        sumsq += v.x * v.x + v.y * v.y + v.z * v.z + v.w * v.w;
    }

    const int lane = threadIdx.x & 63;
    const int wid = threadIdx.x >> 6;
    sum = wave_reduce_sum(sum);
    sumsq = wave_reduce_sum(sumsq);

    __shared__ float sm[2 * (THREADS / 64)];
    if (lane == 0) {
        sm[wid] = sum;
        sm[(THREADS / 64) + wid] = sumsq;
    }
    __syncthreads();
    if (threadIdx.x == 0) {
        ws[2 * blockIdx.x]     = sm[0] + sm[1] + sm[2] + sm[3];
        ws[2 * blockIdx.x + 1] = sm[4] + sm[5] + sm[6] + sm[7];
    }
}

// ---------------- Kernel 2: stats from partials + smooth-L1, per-block partial ----------------
// Student loads are NON-TEMPORAL (read-once stream): keep them from evicting
// the L3-resident teacher. Teacher loads regular -> L3 hits.
__global__ __launch_bounds__(THREADS) void kd_loss_kernel(
    const float4* __restrict__ t, const float4* __restrict__ st,
    const float* __restrict__ ws, float* __restrict__ lpart) {
    const int s = blockIdx.x / BLOCKS_PER_SAMPLE;
    const int lane = threadIdx.x & 63;
    const int wid = threadIdx.x >> 6;

    // Each wave redundantly reduces this sample's 64 partial pairs (L2-hot).
    float psum   = ws[2 * (s * BLOCKS_PER_SAMPLE + lane)];
    float psumsq = ws[2 * (s * BLOCKS_PER_SAMPLE + lane) + 1];
    psum = wave_reduce_sum(psum);
    psumsq = wave_reduce_sum(psumsq);
    psum = __shfl(psum, 0, 64);
    psumsq = __shfl(psumsq, 0, 64);

    const float inv_n = 1.0f / (float)ELEMS_PER_SAMPLE;
    const float mean = psum * inv_n;
    const float var = psumsq * inv_n - mean * mean;
    const float rstd = rsqrtf(var + EPS);

    const size_t off = (size_t)blockIdx.x * (THREADS * ITERS);
    const float4* tb = t + off;
    const f32x4* sb = (const f32x4*)st + off;

    float acc = 0.0f;
#pragma unroll
    for (int i = 0; i < ITERS; ++i) {
        float4 tv = tb[i * THREADS + threadIdx.x];
        f32x4 sv = __builtin_nontemporal_load(sb + i * THREADS + threadIdx.x);

        float d0 = fabsf((tv.x - mean) * rstd - sv.x);
        float d1 = fabsf((tv.y - mean) * rstd - sv.y);
        float d2 = fabsf((tv.z - mean) * rstd - sv.z);
        float d3 = fabsf((tv.w - mean) * rstd - sv.w);

        acc += (d0 <= BETA) ? (0.25f * d0 * d0) : (d0 - 1.0f);
        acc += (d1 <= BETA) ? (0.25f * d1 * d1) : (d1 - 1.0f);
        acc += (d2 <= BETA) ? (0.25f * d2 * d2) : (d2 - 1.0f);
        acc += (d3 <= BETA) ? (0.25f * d3 * d3) : (d3 - 1.0f);
    }

    acc = wave_reduce_sum(acc);
    __shared__ float sm[THREADS / 64];
    if (lane == 0) sm[wid] = acc;
    __syncthreads();
    if (threadIdx.x == 0)
        lpart[blockIdx.x] = sm[0] + sm[1] + sm[2] + sm[3];
}

// ---------------- Kernel 3: final reduce of 2048 partials ----------------
__global__ __launch_bounds__(THREADS) void kd_final_kernel(
    const float* __restrict__ lpart, float* __restrict__ out) {
    float acc = 0.0f;
#pragma unroll
    for (int i = 0; i < GRID / THREADS; ++i)  // 8
        acc += lpart[i * THREADS + threadIdx.x];

    const int lane = threadIdx.x & 63;
    const int wid = threadIdx.x >> 6;
    acc = wave_reduce_sum(acc);
    __shared__ float sm[THREADS / 64];
    if (lane == 0) sm[wid] = acc;
    __syncthreads();
    if (threadIdx.x == 0)
        out[0] = (sm[0] + sm[1] + sm[2] + sm[3]) * (1.0f / (float)SAMPLES);
}

extern "C" void kernel_launch(void* const* d_in, const int* in_sizes, int n_in,
                              void* d_out, int out_size, void* d_ws,
                              size_t ws_size, hipStream_t stream) {
    const float* teacher = (const float*)d_in[0];
    const float* student = (const float*)d_in[1];
    float* out = (float*)d_out;
    float* ws = (float*)d_ws;

    kd_stats_kernel<<<GRID, THREADS, 0, stream>>>((const float4*)teacher, ws);
    kd_loss_kernel<<<GRID, THREADS, 0, stream>>>(
        (const float4*)teacher, (const float4*)student, ws, ws + LPART_OFF);
    kd_final_kernel<<<1, THREADS, 0, stream>>>(ws + LPART_OFF, out);
}